// Round 14
// baseline (1563.373 us; speedup 1.0000x reference)
//
#include <hip/hip_runtime.h>

// B=2048, T=128, D=5, H=256. Two sequential LSTM scans.
// Round 14: R12 (laundered streams, 1131us) + AGPR-resident chunks 0-3.
// The two bugs are now separated: R10 proved AGPR weights + intrinsic MFMA
// are numerically exact; R12 proved the scratch storm was LICM hoisting the
// streamed loads (launder fixes it). Combine: chunks 0-3 in 128 AGPRs/lane
// (unified-file budget at 2 waves/SIMD = 256; arch ~105 + acc 128 fits),
// chunks 4,5 LDS (128 KB), chunks 6,7 streamed+laundered (128 KB/step/CU,
// ~0.9us/step at the 144 GB/s per-CU L2 ceiling vs R12's 384 KB = 2.7us).
// Chain order 0..7,x -> bit-identical numerics (absmax 4.88e-4).
// grid=128 x 512thr, 1 WG/CU, h in XOR-swizzled 8 KB LDS, 2 barriers/step.

typedef __bf16 bf16x8 __attribute__((ext_vector_type(8)));
typedef __bf16 bf16x4 __attribute__((ext_vector_type(4)));
typedef float f32x4 __attribute__((ext_vector_type(4)));
typedef int i32x4 __attribute__((ext_vector_type(4)));

#define MFMA16(A, B, C) __builtin_amdgcn_mfma_f32_16x16x32_bf16((A), (B), (C), 0, 0, 0)

__device__ __forceinline__ float fast_sigmoid(float x) {
  float e = __builtin_amdgcn_exp2f(-1.4426950408889634f * x);
  return __builtin_amdgcn_rcpf(1.0f + e);
}
__device__ __forceinline__ float fast_tanh(float x) {
  float e = __builtin_amdgcn_exp2f(2.8853900817779268f * x);
  return 1.0f - 2.0f * __builtin_amdgcn_rcpf(e + 1.0f);
}
__device__ __forceinline__ float lrelu(float x) { return x >= 0.0f ? x : 0.01f * x; }

__device__ __forceinline__ bf16x8 asbf(i32x4 v) {
  union { i32x4 i; bf16x8 b; } u; u.i = v; return u.b;
}

// ---------------- prep: pack weights ----------------
// Whh frag (gt,c,lane): 8 bf16 = W[g=gt*16+(lane&15)][k=c*32+(lane>>4)*8+0..7]
__global__ void pack_gates_k(const float* __restrict__ Whh, const float* __restrict__ Wih,
                             const float* __restrict__ bih, const float* __restrict__ bhh,
                             __bf16* __restrict__ wpack, __bf16* __restrict__ wih4,
                             __bf16* __restrict__ wihd4, float* __restrict__ bias) {
  int lane = threadIdx.x, blk = blockIdx.x;
  if (blk < 512) {
    int gt = blk >> 3, c = blk & 7;
    int g = gt * 16 + (lane & 15);
    int k0 = c * 32 + (lane >> 4) * 8;
    bf16x8 v;
#pragma unroll
    for (int j = 0; j < 8; ++j) v[j] = (__bf16)Whh[g * 256 + k0 + j];
    *(bf16x8*)(wpack + ((size_t)(gt * 8 + c) * 64 + lane) * 8) = v;
  } else if (blk < 528) {
    int g = (blk - 512) * 64 + lane;
    bf16x4 v;
#pragma unroll
    for (int j = 0; j < 4; ++j) v[j] = (__bf16)Wih[g * 5 + j];
    *(bf16x4*)(wih4 + (size_t)g * 4) = v;
    wihd4[g] = (__bf16)Wih[g * 5 + 4];
  } else {
    int g = (blk - 528) * 64 + lane;
    bias[g] = bih[g] + bhh[g];
  }
}

__global__ void pack_misc_k(const float* __restrict__ Wenc, const float* __restrict__ Wout,
                            __bf16* __restrict__ encpack, __bf16* __restrict__ outd) {
  int lane = threadIdx.x, blk = blockIdx.x;
  if (blk < 128) {  // W_enc[:, :256]: 16 row-tiles x 8 chunks
    int T2 = blk >> 3, c = blk & 7;
    int row = T2 * 16 + (lane & 15);
    int k0 = c * 32 + (lane >> 4) * 8;
    bf16x8 v;
#pragma unroll
    for (int j = 0; j < 8; ++j) v[j] = (__bf16)Wenc[row * 512 + k0 + j];
    *(bf16x8*)(encpack + ((size_t)(T2 * 8 + c) * 64 + lane) * 8) = v;
  } else {  // W_out (5x256) dense, row-XOR-swizzled
    for (int i = lane; i < 1280; i += 64) {
      int row = i >> 8, kk = i & 255;
      outd[row * 256 + (kk ^ (row << 3))] = (__bf16)Wout[row * 256 + kk];
    }
  }
}

// ---------------- main kernel ----------------
// streamed chunks 6,7 for this pass's 4 gate-tiles (issued at pass top)
#define LOADS67(DST, P)                                                              \
  _Pragma("unroll") for (int q = 0; q < 4; ++q) {                                    \
    const int gtq = q * 16 + ut2 + (P);                                              \
    DST[q] = Ws[(gtq * 8 + 6) * 64 + lane];                                          \
    DST[4 + q] = Ws[(gtq * 8 + 7) * 64 + lane];                                      \
  }

// one half-step: gates for tiles (q=0..3, fixed P). Chunk order 0..7,x
// (identical arithmetic to R6/R10/R12). 0-3 AGPR-resident, 4,5 LDS,
// 6,7 streamed (s0, loads issued first for latency cover).
#define GATEPASS(P, AX, HVP)                                                         \
  {                                                                                  \
    i32x4 s0[8];                                                                     \
    LOADS67(s0, P);                                                                  \
    const int gt0 = 0 * 16 + ut2 + (P), gt1 = 1 * 16 + ut2 + (P);                    \
    const int gt2 = 2 * 16 + ut2 + (P), gt3 = 3 * 16 + ut2 + (P);                    \
    const float bv0 = biass[gt0 * 16 + col], bv1 = biass[gt1 * 16 + col];            \
    const float bv2 = biass[gt2 * 16 + col], bv3 = biass[gt3 * 16 + col];            \
    f32x4 a0 = {bv0, bv0, bv0, bv0}, a1 = {bv1, bv1, bv1, bv1};                      \
    f32x4 a2 = {bv2, bv2, bv2, bv2}, a3 = {bv3, bv3, bv3, bv3};                      \
    _Pragma("unroll") for (int c = 0; c < 4; ++c) { /* chunks 0-3: AGPR */           \
      bf16x8 ac = *(const bf16x8*)(hbb + ((col * 512 + c * 64 + lgrp * 16) ^ xsw));  \
      a0 = MFMA16(ac, asbf(wa[(0 * 2 + (P)) * 4 + c]), a0);                          \
      a1 = MFMA16(ac, asbf(wa[(1 * 2 + (P)) * 4 + c]), a1);                          \
      a2 = MFMA16(ac, asbf(wa[(2 * 2 + (P)) * 4 + c]), a2);                          \
      a3 = MFMA16(ac, asbf(wa[(3 * 2 + (P)) * 4 + c]), a3);                          \
    }                                                                                \
    _Pragma("unroll") for (int c2 = 0; c2 < 2; ++c2) { /* chunks 4,5: LDS */         \
      bf16x8 ac = *(const bf16x8*)(hbb + ((col * 512 + (c2 + 4) * 64 + lgrp * 16) ^ xsw)); \
      a0 = MFMA16(ac, *(const bf16x8*)&wlds[c2][gt0][lane][0], a0);                  \
      a1 = MFMA16(ac, *(const bf16x8*)&wlds[c2][gt1][lane][0], a1);                  \
      a2 = MFMA16(ac, *(const bf16x8*)&wlds[c2][gt2][lane][0], a2);                  \
      a3 = MFMA16(ac, *(const bf16x8*)&wlds[c2][gt3][lane][0], a3);                  \
    }                                                                                \
    { /* chunks 6,7: streamed (s0) */                                                \
      bf16x8 ac6 = *(const bf16x8*)(hbb + ((col * 512 + 6 * 64 + lgrp * 16) ^ xsw)); \
      a0 = MFMA16(ac6, asbf(s0[0]), a0); a1 = MFMA16(ac6, asbf(s0[1]), a1);          \
      a2 = MFMA16(ac6, asbf(s0[2]), a2); a3 = MFMA16(ac6, asbf(s0[3]), a3);          \
      bf16x8 ac7 = *(const bf16x8*)(hbb + ((col * 512 + 7 * 64 + lgrp * 16) ^ xsw)); \
      a0 = MFMA16(ac7, asbf(s0[4]), a0); a1 = MFMA16(ac7, asbf(s0[5]), a1);          \
      a2 = MFMA16(ac7, asbf(s0[6]), a2); a3 = MFMA16(ac7, asbf(s0[7]), a3);          \
    }                                                                                \
    { /* x chunk last */                                                             \
      bf16x8 b0f = {}, b1f = {}, b2f = {}, b3f = {};                                 \
      if (lgrp == 0) {                                                               \
        bf16x4 w40 = *(const bf16x4*)&wih4s[gt0 * 16 + col][0];                      \
        bf16x4 w41 = *(const bf16x4*)&wih4s[gt1 * 16 + col][0];                      \
        bf16x4 w42 = *(const bf16x4*)&wih4s[gt2 * 16 + col][0];                      \
        bf16x4 w43 = *(const bf16x4*)&wih4s[gt3 * 16 + col][0];                      \
        b0f[0]=w40[0]; b0f[1]=w40[1]; b0f[2]=w40[2]; b0f[3]=w40[3];                  \
        b1f[0]=w41[0]; b1f[1]=w41[1]; b1f[2]=w41[2]; b1f[3]=w41[3];                  \
        b2f[0]=w42[0]; b2f[1]=w42[1]; b2f[2]=w42[2]; b2f[3]=w42[3];                  \
        b3f[0]=w43[0]; b3f[1]=w43[1]; b3f[2]=w43[2]; b3f[3]=w43[3];                  \
        b0f[4]=wihd4s[gt0 * 16 + col]; b1f[4]=wihd4s[gt1 * 16 + col];                \
        b2f[4]=wihd4s[gt2 * 16 + col]; b3f[4]=wihd4s[gt3 * 16 + col];                \
      }                                                                              \
      a0 = MFMA16(AX, b0f, a0); a1 = MFMA16(AX, b1f, a1);                            \
      a2 = MFMA16(AX, b2f, a2); a3 = MFMA16(AX, b3f, a3);                            \
    }                                                                                \
    _Pragma("unroll") for (int r = 0; r < 4; ++r) {                                  \
      float ig = fast_sigmoid(a0[r]);                                                \
      float fg = fast_sigmoid(a1[r]);                                                \
      float gg = fast_tanh(a2[r]);                                                   \
      float og = fast_sigmoid(a3[r]);                                                \
      float cn = fg * c_reg[P][r] + ig * gg;                                         \
      c_reg[P][r] = cn;                                                              \
      HVP[r] = og * fast_tanh(cn);                                                   \
    }                                                                                \
  }

#define HWRITE2(HV)                                                                    \
  _Pragma("unroll") for (int P = 0; P < 2; ++P)                                        \
  _Pragma("unroll") for (int r = 0; r < 4; ++r) {                                      \
    const int row = lgrp * 4 + r;                                                      \
    const int u = 32 * wv + 16 * P + col;                                              \
    *(__bf16*)(hbb + ((row * 512 + u * 2) ^ ((row & 7) << 4))) = (__bf16)HV[P][r];     \
  }

__global__ __launch_bounds__(512) void rnn_agl(
    const float* __restrict__ sk, const float* __restrict__ initx,
    const i32x4* __restrict__ Wg, const __bf16* __restrict__ Wih4g, const __bf16* __restrict__ Wihd4g,
    const float* __restrict__ Bg,
    const i32x4* __restrict__ Wf, const __bf16* __restrict__ Wih4f, const __bf16* __restrict__ Wihd4f,
    const float* __restrict__ Bf,
    const bf16x8* __restrict__ Epk, const float* __restrict__ benc,
    const __bf16* __restrict__ Od, const float* __restrict__ bout,
    float* __restrict__ out) {
  __shared__ __attribute__((aligned(16))) __bf16 wlds[2][64][64][8];  // 131072 B: chunks 4,5
  __shared__ __attribute__((aligned(16))) __bf16 wih4s[1024][4];      // 8192 B
  __shared__ __attribute__((aligned(16))) __bf16 hb[4096];            // 8192 B
  __shared__ __attribute__((aligned(16))) float biass[1024];          // 4096 B
  __shared__ __attribute__((aligned(16))) __bf16 woutd[5][256];       // 2560 B
  __shared__ __attribute__((aligned(16))) __bf16 wihd4s[1024];        // 2048 B
  __shared__ __attribute__((aligned(16))) __bf16 xts[8][16][8];       // 2048 B

  const int tid = threadIdx.x, lane = tid & 63, wv = tid >> 6;
  const int col = lane & 15, lgrp = lane >> 4;
  const int b0 = blockIdx.x * 16;
  const int ut2 = wv * 2;
  const int xsw = (col & 7) << 4;
  char* hbb = (char*)hb;
  char* wob = (char*)woutd;

  auto stage_wlds = [&](const i32x4* Wpk) {  // chunks 4,5 -> LDS
    for (int i = tid; i < 8192; i += 512) {
      int c2 = i >> 12, gt = (i >> 6) & 63, ln = i & 63;
      *(i32x4*)&wlds[c2][gt][ln][0] = Wpk[(gt * 8 + 4 + c2) * 64 + ln];
    }
  };
  auto stage_small = [&](const __bf16* w4, const __bf16* wd4, const float* Bp) {
    for (int i = tid; i < 1024; i += 512) {
      *(bf16x4*)&wih4s[i][0] = *(const bf16x4*)(w4 + (size_t)i * 4);
      wihd4s[i] = wd4[i];
      biass[i] = Bp[i];
    }
  };

  // ---------- encoder prologue ----------
  stage_wlds(Wf);
  stage_small(Wih4f, Wihd4f, Bf);
  for (int i = tid; i < 4096; i += 512) hb[i] = (__bf16)0.0f;
  for (int i = tid; i < 1024; i += 512) (&xts[0][0][0])[i] = (__bf16)0.0f;

  const i32x4* Ws = Wf;  // stream base (chunks 6,7)

  // W_hh chunks 0..3 -> AGPR (32 quads = 128 AGPRs/lane), consumed by intrinsics
  i32x4 wa[32];
#pragma unroll
  for (int m = 0; m < 8; ++m) {
    const int gt = (m >> 1) * 16 + ut2 + (m & 1);
#pragma unroll
    for (int c = 0; c < 4; ++c) wa[m * 4 + c] = Wf[(gt * 8 + c) * 64 + lane];
  }
#pragma unroll
  for (int i = 0; i < 32; ++i) asm volatile("" : "+a"(wa[i]));  // pin to AGPR class

  float c_reg[2][4] = {{0.f, 0.f, 0.f, 0.f}, {0.f, 0.f, 0.f, 0.f}};
  float xc0 = 0.f, xc1 = 0.f, xc2 = 0.f, xc3 = 0.f, xc4 = 0.f;
  if (lgrp == 0) {
    const float* xp = sk + (size_t)(b0 + col) * 128 * 5;
    xc0 = xp[0]; xc1 = xp[1]; xc2 = xp[2]; xc3 = xp[3]; xc4 = xp[4];
  }
  __syncthreads();

  // -------- encoder: 128 steps --------
#pragma unroll 1
  for (int t = 0; t < 128; ++t) {
    asm volatile("" : "+s"(Ws));  // launder: defeat cross-step hoist (R12 fix)
    bf16x8 ax = (bf16x8){};
    if (lgrp == 0) {
      ax[0] = (__bf16)xc0; ax[1] = (__bf16)xc1; ax[2] = (__bf16)xc2;
      ax[3] = (__bf16)xc3; ax[4] = (__bf16)xc4;
    }
    if (t < 127 && lgrp == 0) {  // prefetch x(t+1) under the MFMA chain
      const float* xp = sk + ((size_t)(b0 + col) * 128 + t + 1) * 5;
      xc0 = xp[0]; xc1 = xp[1]; xc2 = xp[2]; xc3 = xp[3]; xc4 = xp[4];
    }
    float hv[2][4];
    GATEPASS(0, ax, hv[0]);
    GATEPASS(1, ax, hv[1]);
    __syncthreads();  // all reads of h(t) done
    HWRITE2(hv);
    __syncthreads();  // h(t+1) visible
  }

  // -------- transition --------
  bf16x8 ah[8];
#pragma unroll
  for (int c = 0; c < 8; ++c)
    ah[c] = *(const bf16x8*)(hbb + ((col * 512 + c * 64 + lgrp * 16) ^ xsw));
  __syncthreads();
#pragma unroll
  for (int P = 0; P < 2; ++P)
#pragma unroll
    for (int r = 0; r < 4; ++r) {
      const int row = lgrp * 4 + r;
      const int u = 32 * wv + 16 * P + col;
      *(__bf16*)(hbb + ((row * 512 + u * 2) ^ ((row & 7) << 4))) = (__bf16)c_reg[P][r];
    }
  __syncthreads();
  bf16x8 acf[8];
#pragma unroll
  for (int c = 0; c < 8; ++c)
    acf[c] = *(const bf16x8*)(hbb + ((col * 512 + c * 64 + lgrp * 16) ^ xsw));
  __syncthreads();  // hb free

  float hvt[2][4];
#pragma unroll
  for (int p = 0; p < 2; ++p) {
    const int T2 = ut2 + p;
    const float bvh = benc[T2 * 16 + col];
    f32x4 hacc = {bvh, bvh, bvh, bvh};
    f32x4 cacc = {bvh, bvh, bvh, bvh};
#pragma unroll
    for (int c = 0; c < 8; ++c) {
      bf16x8 eb = Epk[(T2 * 8 + c) * 64 + lane];
      hacc = MFMA16(ah[c], eb, hacc);
      cacc = MFMA16(acf[c], eb, cacc);
    }
#pragma unroll
    for (int r = 0; r < 4; ++r) {
      hvt[p][r] = lrelu(hacc[r]);
      c_reg[p][r] = lrelu(cacc[r]);  // gen c(0)
    }
  }
  HWRITE2(hvt);  // gen h(0)

  // restage for generator
  stage_wlds(Wg);
  stage_small(Wih4g, Wihd4g, Bg);
  for (int i = tid; i < 1280; i += 512) (&woutd[0][0])[i] = Od[i];
  Ws = Wg;
#pragma unroll
  for (int m = 0; m < 8; ++m) {
    const int gt = (m >> 1) * 16 + ut2 + (m & 1);
#pragma unroll
    for (int c = 0; c < 4; ++c) wa[m * 4 + c] = Wg[(gt * 8 + c) * 64 + lane];
  }
#pragma unroll
  for (int i = 0; i < 32; ++i) asm volatile("" : "+a"(wa[i]));

  const float bo = (col < 5) ? bout[col] : 0.0f;
  bf16x8 ax = (bf16x8){};
  if (lgrp == 0) {
    const float* xp = initx + (size_t)(b0 + col) * 5;
    ax[0] = (__bf16)xp[0]; ax[1] = (__bf16)xp[1]; ax[2] = (__bf16)xp[2];
    ax[3] = (__bf16)xp[3]; ax[4] = (__bf16)xp[4];
  }
  __syncthreads();  // h(0) + gen stages visible

  // -------- generator: 128 steps --------
  const int orow = (col < 5) ? col : 0;
#pragma unroll 1
  for (int j = 0; j < 128; ++j) {
    asm volatile("" : "+s"(Ws));  // launder
    float hv[2][4];
    GATEPASS(0, ax, hv[0]);
    GATEPASS(1, ax, hv[1]);
    __syncthreads();  // reads of h(j) done
    HWRITE2(hv);
    __syncthreads();  // h(j+1) visible
    // out(j) = lrelu(W_out @ h(j+1) + b_out), all waves (private x-transpose)
    f32x4 oacc = {bo, bo, bo, bo};
#pragma unroll
    for (int c = 0; c < 8; ++c) {
      bf16x8 ac = *(const bf16x8*)(hbb + ((col * 512 + c * 64 + lgrp * 16) ^ xsw));
      bf16x8 wb = *(const bf16x8*)(wob + (orow * 512 + ((c * 64 + lgrp * 16) ^ (orow << 4))));
      oacc = MFMA16(ac, wb, oacc);
    }
    if (col < 5) {
#pragma unroll
      for (int r = 0; r < 4; ++r) {
        float v = lrelu(oacc[r]);
        if (wv == 0) out[((size_t)(b0 + lgrp * 4 + r) * 128 + j) * 5 + col] = v;
        xts[wv][lgrp * 4 + r][col] = (__bf16)v;  // cols 5..7 stay zero
      }
    }
    ax = (bf16x8){};
    if (lgrp == 0) ax = *(const bf16x8*)&xts[wv][col][0];
  }
}

extern "C" void kernel_launch(void* const* d_in, const int* in_sizes, int n_in,
                              void* d_out, int out_size, void* d_ws, size_t ws_size,
                              hipStream_t stream) {
  const float* sk = (const float*)d_in[0];
  const float* initx = (const float*)d_in[1];
  const float* W_ih = (const float*)d_in[2];
  const float* W_hh = (const float*)d_in[3];
  const float* b_ih = (const float*)d_in[4];
  const float* b_hh = (const float*)d_in[5];
  const float* W_ih_f = (const float*)d_in[6];
  const float* W_hh_f = (const float*)d_in[7];
  const float* b_ih_f = (const float*)d_in[8];
  const float* b_hh_f = (const float*)d_in[9];
  const float* W_enc = (const float*)d_in[14];
  const float* b_enc = (const float*)d_in[15];
  const float* W_out = (const float*)d_in[16];
  const float* b_out = (const float*)d_in[17];

  char* ws = (char*)d_ws;
  __bf16* Wg = (__bf16*)(ws + 0);            // 524288
  __bf16* Wf = (__bf16*)(ws + 524288);       // 524288
  __bf16* Wih4g = (__bf16*)(ws + 1048576);   // 8192
  __bf16* Wihd4g = (__bf16*)(ws + 1056768);  // 2048
  __bf16* Wih4f = (__bf16*)(ws + 1058816);   // 8192
  __bf16* Wihd4f = (__bf16*)(ws + 1067008);  // 2048
  float* Bg = (float*)(ws + 1069056);        // 4096
  float* Bf = (float*)(ws + 1073152);        // 4096
  __bf16* Epk = (__bf16*)(ws + 1077248);     // 131072
  __bf16* Od = (__bf16*)(ws + 1208320);      // 2560

  pack_gates_k<<<544, 64, 0, stream>>>(W_hh, W_ih, b_ih, b_hh, Wg, Wih4g, Wihd4g, Bg);
  pack_gates_k<<<544, 64, 0, stream>>>(W_hh_f, W_ih_f, b_ih_f, b_hh_f, Wf, Wih4f, Wihd4f, Bf);
  pack_misc_k<<<129, 64, 0, stream>>>(W_enc, W_out, Epk, Od);

  rnn_agl<<<128, 512, 0, stream>>>(
      sk, initx,
      (const i32x4*)Wg, Wih4g, Wihd4g, Bg,
      (const i32x4*)Wf, Wih4f, Wihd4f, Bf,
      (const bf16x8*)Epk, b_enc,
      Od, b_out,
      (float*)d_out);
}

// Round 15
// 1201.145 us; speedup vs baseline: 1.3016x; 1.3016x over previous
//
#include <hip/hip_runtime.h>

// B=2048, T=128, D=5, H=256. Two sequential LSTM scans.
// Round 15: R12 (best, 1131us) + deep in-step load pipeline. All 24 quads of
// pass0 issued at step top (A0/A1/A2); pass1's 24 quads (B0/B1/B2) issued
// interleaved under pass0's MFMA chain -> single L2-latency stall per step
// instead of ~4. No loop-carried weight regs (R4-R14: those always spill).
// Chunks 4,5 LDS-resident; 0,1,2,3,6,7 streamed via laundered base (LICM
// defeat, R12). Chain order 0..7,x per tile -> bit-identical numerics.
// grid=128 x 512thr, 1 WG/CU, h in XOR-swizzled 8 KB LDS, 2 barriers/step.

typedef __bf16 bf16x8 __attribute__((ext_vector_type(8)));
typedef __bf16 bf16x4 __attribute__((ext_vector_type(4)));
typedef float f32x4 __attribute__((ext_vector_type(4)));
typedef int i32x4 __attribute__((ext_vector_type(4)));

#define MFMA16(A, B, C) __builtin_amdgcn_mfma_f32_16x16x32_bf16((A), (B), (C), 0, 0, 0)

__device__ __forceinline__ float fast_sigmoid(float x) {
  float e = __builtin_amdgcn_exp2f(-1.4426950408889634f * x);
  return __builtin_amdgcn_rcpf(1.0f + e);
}
__device__ __forceinline__ float fast_tanh(float x) {
  float e = __builtin_amdgcn_exp2f(2.8853900817779268f * x);
  return 1.0f - 2.0f * __builtin_amdgcn_rcpf(e + 1.0f);
}
__device__ __forceinline__ float lrelu(float x) { return x >= 0.0f ? x : 0.01f * x; }

__device__ __forceinline__ bf16x8 asbf(i32x4 v) {
  union { i32x4 i; bf16x8 b; } u; u.i = v; return u.b;
}

// ---------------- prep: pack weights ----------------
// Whh frag (gt,c,lane): 8 bf16 = W[g=gt*16+(lane&15)][k=c*32+(lane>>4)*8+0..7]
__global__ void pack_gates_k(const float* __restrict__ Whh, const float* __restrict__ Wih,
                             const float* __restrict__ bih, const float* __restrict__ bhh,
                             __bf16* __restrict__ wpack, __bf16* __restrict__ wih4,
                             __bf16* __restrict__ wihd4, float* __restrict__ bias) {
  int lane = threadIdx.x, blk = blockIdx.x;
  if (blk < 512) {
    int gt = blk >> 3, c = blk & 7;
    int g = gt * 16 + (lane & 15);
    int k0 = c * 32 + (lane >> 4) * 8;
    bf16x8 v;
#pragma unroll
    for (int j = 0; j < 8; ++j) v[j] = (__bf16)Whh[g * 256 + k0 + j];
    *(bf16x8*)(wpack + ((size_t)(gt * 8 + c) * 64 + lane) * 8) = v;
  } else if (blk < 528) {
    int g = (blk - 512) * 64 + lane;
    bf16x4 v;
#pragma unroll
    for (int j = 0; j < 4; ++j) v[j] = (__bf16)Wih[g * 5 + j];
    *(bf16x4*)(wih4 + (size_t)g * 4) = v;
    wihd4[g] = (__bf16)Wih[g * 5 + 4];
  } else {
    int g = (blk - 528) * 64 + lane;
    bias[g] = bih[g] + bhh[g];
  }
}

__global__ void pack_misc_k(const float* __restrict__ Wenc, const float* __restrict__ Wout,
                            __bf16* __restrict__ encpack, __bf16* __restrict__ outd) {
  int lane = threadIdx.x, blk = blockIdx.x;
  if (blk < 128) {  // W_enc[:, :256]: 16 row-tiles x 8 chunks
    int T2 = blk >> 3, c = blk & 7;
    int row = T2 * 16 + (lane & 15);
    int k0 = c * 32 + (lane >> 4) * 8;
    bf16x8 v;
#pragma unroll
    for (int j = 0; j < 8; ++j) v[j] = (__bf16)Wenc[row * 512 + k0 + j];
    *(bf16x8*)(encpack + ((size_t)(T2 * 8 + c) * 64 + lane) * 8) = v;
  } else {  // W_out (5x256) dense, row-XOR-swizzled
    for (int i = lane; i < 1280; i += 64) {
      int row = i >> 8, kk = i & 255;
      outd[row * 256 + (kk ^ (row << 3))] = (__bf16)Wout[row * 256 + kk];
    }
  }
}

// ---------------- main kernel ----------------
#define LOADQ(DST, P, CA, CB)                                                        \
  _Pragma("unroll") for (int q = 0; q < 4; ++q) {                                    \
    const int gtq = q * 16 + ut2 + (P);                                              \
    DST[q] = Ws[(gtq * 8 + (CA)) * 64 + lane];                                       \
    DST[4 + q] = Ws[(gtq * 8 + (CB)) * 64 + lane];                                   \
  }

// 4 MFMAs for one h-chunk C against fragment quads F0..F3
#define CHMF(C, F0, F1, F2, F3)                                                      \
  { bf16x8 ac = *(const bf16x8*)(hbb + ((col * 512 + (C) * 64 + lgrp * 16) ^ xsw));  \
    a0 = MFMA16(ac, asbf(F0), a0); a1 = MFMA16(ac, asbf(F1), a1);                    \
    a2 = MFMA16(ac, asbf(F2), a2); a3 = MFMA16(ac, asbf(F3), a3); }

// LDS chunks 4,5 + x-chunk + activations for pass P (accs a0..a3 in scope)
#define PASS_TAIL(P, AX, HVP)                                                        \
  {                                                                                  \
    const int gt0 = 0 * 16 + ut2 + (P), gt1 = 1 * 16 + ut2 + (P);                    \
    const int gt2 = 2 * 16 + ut2 + (P), gt3 = 3 * 16 + ut2 + (P);                    \
    _Pragma("unroll") for (int c2 = 0; c2 < 2; ++c2) {                               \
      bf16x8 ac = *(const bf16x8*)(hbb + ((col * 512 + (c2 + 4) * 64 + lgrp * 16) ^ xsw)); \
      a0 = MFMA16(ac, *(const bf16x8*)&wlds[c2][gt0][lane][0], a0);                  \
      a1 = MFMA16(ac, *(const bf16x8*)&wlds[c2][gt1][lane][0], a1);                  \
      a2 = MFMA16(ac, *(const bf16x8*)&wlds[c2][gt2][lane][0], a2);                  \
      a3 = MFMA16(ac, *(const bf16x8*)&wlds[c2][gt3][lane][0], a3);                  \
    }                                                                                \
  }

#define PASS_X_ACT(P, AX, HVP)                                                       \
  {                                                                                  \
    const int gt0 = 0 * 16 + ut2 + (P), gt1 = 1 * 16 + ut2 + (P);                    \
    const int gt2 = 2 * 16 + ut2 + (P), gt3 = 3 * 16 + ut2 + (P);                    \
    bf16x8 b0f = {}, b1f = {}, b2f = {}, b3f = {};                                   \
    if (lgrp == 0) {                                                                 \
      bf16x4 w40 = *(const bf16x4*)&wih4s[gt0 * 16 + col][0];                        \
      bf16x4 w41 = *(const bf16x4*)&wih4s[gt1 * 16 + col][0];                        \
      bf16x4 w42 = *(const bf16x4*)&wih4s[gt2 * 16 + col][0];                        \
      bf16x4 w43 = *(const bf16x4*)&wih4s[gt3 * 16 + col][0];                        \
      b0f[0]=w40[0]; b0f[1]=w40[1]; b0f[2]=w40[2]; b0f[3]=w40[3];                    \
      b1f[0]=w41[0]; b1f[1]=w41[1]; b1f[2]=w41[2]; b1f[3]=w41[3];                    \
      b2f[0]=w42[0]; b2f[1]=w42[1]; b2f[2]=w42[2]; b2f[3]=w42[3];                    \
      b3f[0]=w43[0]; b3f[1]=w43[1]; b3f[2]=w43[2]; b3f[3]=w43[3];                    \
      b0f[4]=wihd4s[gt0 * 16 + col]; b1f[4]=wihd4s[gt1 * 16 + col];                  \
      b2f[4]=wihd4s[gt2 * 16 + col]; b3f[4]=wihd4s[gt3 * 16 + col];                  \
    }                                                                                \
    a0 = MFMA16(AX, b0f, a0); a1 = MFMA16(AX, b1f, a1);                              \
    a2 = MFMA16(AX, b2f, a2); a3 = MFMA16(AX, b3f, a3);                              \
    _Pragma("unroll") for (int r = 0; r < 4; ++r) {                                  \
      float ig = fast_sigmoid(a0[r]);                                                \
      float fg = fast_sigmoid(a1[r]);                                                \
      float gg = fast_tanh(a2[r]);                                                   \
      float og = fast_sigmoid(a3[r]);                                                \
      float cn = fg * c_reg[P][r] + ig * gg;                                         \
      c_reg[P][r] = cn;                                                              \
      HVP[r] = og * fast_tanh(cn);                                                   \
    }                                                                                \
  }

#define ACC_INIT(P)                                                                  \
  const float bv0 = biass[(0 * 16 + ut2 + (P)) * 16 + col];                          \
  const float bv1 = biass[(1 * 16 + ut2 + (P)) * 16 + col];                          \
  const float bv2 = biass[(2 * 16 + ut2 + (P)) * 16 + col];                          \
  const float bv3 = biass[(3 * 16 + ut2 + (P)) * 16 + col];                          \
  f32x4 a0 = {bv0, bv0, bv0, bv0}, a1 = {bv1, bv1, bv1, bv1};                        \
  f32x4 a2 = {bv2, bv2, bv2, bv2}, a3 = {bv3, bv3, bv3, bv3};

// one full step: pass0 loads up-front; pass1 loads issued under pass0 MFMAs.
#define STEP(AX, HV)                                                                 \
  {                                                                                  \
    i32x4 A0[8], A1[8], A2[8];                                                       \
    LOADQ(A0, 0, 0, 1);                                                              \
    LOADQ(A1, 0, 2, 3);                                                              \
    LOADQ(A2, 0, 6, 7);                                                              \
    i32x4 B0[8], B1[8], B2[8];                                                       \
    { /* pass 0 */                                                                   \
      ACC_INIT(0);                                                                   \
      CHMF(0, A0[0], A0[1], A0[2], A0[3]);                                           \
      CHMF(1, A0[4], A0[5], A0[6], A0[7]);                                           \
      LOADQ(B0, 1, 0, 1);                                                            \
      CHMF(2, A1[0], A1[1], A1[2], A1[3]);                                           \
      CHMF(3, A1[4], A1[5], A1[6], A1[7]);                                           \
      LOADQ(B1, 1, 2, 3);                                                            \
      PASS_TAIL(0, AX, HV[0]);                                                       \
      CHMF(6, A2[0], A2[1], A2[2], A2[3]);                                           \
      CHMF(7, A2[4], A2[5], A2[6], A2[7]);                                           \
      LOADQ(B2, 1, 6, 7);                                                            \
      PASS_X_ACT(0, AX, HV[0]);                                                      \
    }                                                                                \
    { /* pass 1 */                                                                   \
      ACC_INIT(1);                                                                   \
      CHMF(0, B0[0], B0[1], B0[2], B0[3]);                                           \
      CHMF(1, B0[4], B0[5], B0[6], B0[7]);                                           \
      CHMF(2, B1[0], B1[1], B1[2], B1[3]);                                           \
      CHMF(3, B1[4], B1[5], B1[6], B1[7]);                                           \
      PASS_TAIL(1, AX, HV[1]);                                                       \
      CHMF(6, B2[0], B2[1], B2[2], B2[3]);                                           \
      CHMF(7, B2[4], B2[5], B2[6], B2[7]);                                           \
      PASS_X_ACT(1, AX, HV[1]);                                                      \
    }                                                                                \
  }

#define HWRITE2(HV)                                                                    \
  _Pragma("unroll") for (int P = 0; P < 2; ++P)                                        \
  _Pragma("unroll") for (int r = 0; r < 4; ++r) {                                      \
    const int row = lgrp * 4 + r;                                                      \
    const int u = 32 * wv + 16 * P + col;                                              \
    *(__bf16*)(hbb + ((row * 512 + u * 2) ^ ((row & 7) << 4))) = (__bf16)HV[P][r];     \
  }

__global__ __launch_bounds__(512) void rnn_pp(
    const float* __restrict__ sk, const float* __restrict__ initx,
    const i32x4* __restrict__ Wg, const __bf16* __restrict__ Wih4g, const __bf16* __restrict__ Wihd4g,
    const float* __restrict__ Bg,
    const i32x4* __restrict__ Wf, const __bf16* __restrict__ Wih4f, const __bf16* __restrict__ Wihd4f,
    const float* __restrict__ Bf,
    const bf16x8* __restrict__ Epk, const float* __restrict__ benc,
    const __bf16* __restrict__ Od, const float* __restrict__ bout,
    float* __restrict__ out) {
  __shared__ __attribute__((aligned(16))) __bf16 wlds[2][64][64][8];  // 131072 B: chunks 4,5
  __shared__ __attribute__((aligned(16))) __bf16 wih4s[1024][4];      // 8192 B
  __shared__ __attribute__((aligned(16))) __bf16 hb[4096];            // 8192 B
  __shared__ __attribute__((aligned(16))) float biass[1024];          // 4096 B
  __shared__ __attribute__((aligned(16))) __bf16 woutd[5][256];       // 2560 B
  __shared__ __attribute__((aligned(16))) __bf16 wihd4s[1024];        // 2048 B
  __shared__ __attribute__((aligned(16))) __bf16 xts[8][16][8];       // 2048 B

  const int tid = threadIdx.x, lane = tid & 63, wv = tid >> 6;
  const int col = lane & 15, lgrp = lane >> 4;
  const int b0 = blockIdx.x * 16;
  const int ut2 = wv * 2;
  const int xsw = (col & 7) << 4;
  char* hbb = (char*)hb;
  char* wob = (char*)woutd;

  auto stage_wlds = [&](const i32x4* Wpk) {  // chunks 4,5 -> LDS
    for (int i = tid; i < 8192; i += 512) {
      int c2 = i >> 12, gt = (i >> 6) & 63, ln = i & 63;
      *(i32x4*)&wlds[c2][gt][ln][0] = Wpk[(gt * 8 + 4 + c2) * 64 + ln];
    }
  };
  auto stage_small = [&](const __bf16* w4, const __bf16* wd4, const float* Bp) {
    for (int i = tid; i < 1024; i += 512) {
      *(bf16x4*)&wih4s[i][0] = *(const bf16x4*)(w4 + (size_t)i * 4);
      wihd4s[i] = wd4[i];
      biass[i] = Bp[i];
    }
  };

  // ---------- encoder prologue ----------
  stage_wlds(Wf);
  stage_small(Wih4f, Wihd4f, Bf);
  for (int i = tid; i < 4096; i += 512) hb[i] = (__bf16)0.0f;
  for (int i = tid; i < 1024; i += 512) (&xts[0][0][0])[i] = (__bf16)0.0f;

  const i32x4* Ws = Wf;  // stream base (chunks 0-3,6,7)

  float c_reg[2][4] = {{0.f, 0.f, 0.f, 0.f}, {0.f, 0.f, 0.f, 0.f}};
  float xc0 = 0.f, xc1 = 0.f, xc2 = 0.f, xc3 = 0.f, xc4 = 0.f;
  if (lgrp == 0) {
    const float* xp = sk + (size_t)(b0 + col) * 128 * 5;
    xc0 = xp[0]; xc1 = xp[1]; xc2 = xp[2]; xc3 = xp[3]; xc4 = xp[4];
  }
  __syncthreads();

  // -------- encoder: 128 steps --------
#pragma unroll 1
  for (int t = 0; t < 128; ++t) {
    asm volatile("" : "+s"(Ws));  // launder: defeat cross-step hoist (R12 fix)
    bf16x8 ax = (bf16x8){};
    if (lgrp == 0) {
      ax[0] = (__bf16)xc0; ax[1] = (__bf16)xc1; ax[2] = (__bf16)xc2;
      ax[3] = (__bf16)xc3; ax[4] = (__bf16)xc4;
    }
    if (t < 127 && lgrp == 0) {  // prefetch x(t+1) under the MFMA chain
      const float* xp = sk + ((size_t)(b0 + col) * 128 + t + 1) * 5;
      xc0 = xp[0]; xc1 = xp[1]; xc2 = xp[2]; xc3 = xp[3]; xc4 = xp[4];
    }
    float hv[2][4];
    STEP(ax, hv);
    __syncthreads();  // all reads of h(t) done
    HWRITE2(hv);
    __syncthreads();  // h(t+1) visible
  }

  // -------- transition --------
  bf16x8 ah[8];
#pragma unroll
  for (int c = 0; c < 8; ++c)
    ah[c] = *(const bf16x8*)(hbb + ((col * 512 + c * 64 + lgrp * 16) ^ xsw));
  __syncthreads();
#pragma unroll
  for (int P = 0; P < 2; ++P)
#pragma unroll
    for (int r = 0; r < 4; ++r) {
      const int row = lgrp * 4 + r;
      const int u = 32 * wv + 16 * P + col;
      *(__bf16*)(hbb + ((row * 512 + u * 2) ^ ((row & 7) << 4))) = (__bf16)c_reg[P][r];
    }
  __syncthreads();
  bf16x8 acf[8];
#pragma unroll
  for (int c = 0; c < 8; ++c)
    acf[c] = *(const bf16x8*)(hbb + ((col * 512 + c * 64 + lgrp * 16) ^ xsw));
  __syncthreads();  // hb free

  float hvt[2][4];
#pragma unroll
  for (int p = 0; p < 2; ++p) {
    const int T2 = ut2 + p;
    const float bvh = benc[T2 * 16 + col];
    f32x4 hacc = {bvh, bvh, bvh, bvh};
    f32x4 cacc = {bvh, bvh, bvh, bvh};
#pragma unroll
    for (int c = 0; c < 8; ++c) {
      bf16x8 eb = Epk[(T2 * 8 + c) * 64 + lane];
      hacc = MFMA16(ah[c], eb, hacc);
      cacc = MFMA16(acf[c], eb, cacc);
    }
#pragma unroll
    for (int r = 0; r < 4; ++r) {
      hvt[p][r] = lrelu(hacc[r]);
      c_reg[p][r] = lrelu(cacc[r]);  // gen c(0)
    }
  }
  HWRITE2(hvt);  // gen h(0)

  // restage for generator
  stage_wlds(Wg);
  stage_small(Wih4g, Wihd4g, Bg);
  for (int i = tid; i < 1280; i += 512) (&woutd[0][0])[i] = Od[i];
  Ws = Wg;

  const float bo = (col < 5) ? bout[col] : 0.0f;
  bf16x8 ax = (bf16x8){};
  if (lgrp == 0) {
    const float* xp = initx + (size_t)(b0 + col) * 5;
    ax[0] = (__bf16)xp[0]; ax[1] = (__bf16)xp[1]; ax[2] = (__bf16)xp[2];
    ax[3] = (__bf16)xp[3]; ax[4] = (__bf16)xp[4];
  }
  __syncthreads();  // h(0) + gen stages visible

  // -------- generator: 128 steps --------
  const int orow = (col < 5) ? col : 0;
#pragma unroll 1
  for (int j = 0; j < 128; ++j) {
    asm volatile("" : "+s"(Ws));  // launder
    float hv[2][4];
    STEP(ax, hv);
    __syncthreads();  // reads of h(j) done
    HWRITE2(hv);
    __syncthreads();  // h(j+1) visible
    // out(j) = lrelu(W_out @ h(j+1) + b_out), all waves (private x-transpose)
    f32x4 oacc = {bo, bo, bo, bo};
#pragma unroll
    for (int c = 0; c < 8; ++c) {
      bf16x8 ac = *(const bf16x8*)(hbb + ((col * 512 + c * 64 + lgrp * 16) ^ xsw));
      bf16x8 wb = *(const bf16x8*)(wob + (orow * 512 + ((c * 64 + lgrp * 16) ^ (orow << 4))));
      oacc = MFMA16(ac, wb, oacc);
    }
    if (col < 5) {
#pragma unroll
      for (int r = 0; r < 4; ++r) {
        float v = lrelu(oacc[r]);
        if (wv == 0) out[((size_t)(b0 + lgrp * 4 + r) * 128 + j) * 5 + col] = v;
        xts[wv][lgrp * 4 + r][col] = (__bf16)v;  // cols 5..7 stay zero
      }
    }
    ax = (bf16x8){};
    if (lgrp == 0) ax = *(const bf16x8*)&xts[wv][col][0];
  }
}

extern "C" void kernel_launch(void* const* d_in, const int* in_sizes, int n_in,
                              void* d_out, int out_size, void* d_ws, size_t ws_size,
                              hipStream_t stream) {
  const float* sk = (const float*)d_in[0];
  const float* initx = (const float*)d_in[1];
  const float* W_ih = (const float*)d_in[2];
  const float* W_hh = (const float*)d_in[3];
  const float* b_ih = (const float*)d_in[4];
  const float* b_hh = (const float*)d_in[5];
  const float* W_ih_f = (const float*)d_in[6];
  const float* W_hh_f = (const float*)d_in[7];
  const float* b_ih_f = (const float*)d_in[8];
  const float* b_hh_f = (const float*)d_in[9];
  const float* W_enc = (const float*)d_in[14];
  const float* b_enc = (const float*)d_in[15];
  const float* W_out = (const float*)d_in[16];
  const float* b_out = (const float*)d_in[17];

  char* ws = (char*)d_ws;
  __bf16* Wg = (__bf16*)(ws + 0);            // 524288
  __bf16* Wf = (__bf16*)(ws + 524288);       // 524288
  __bf16* Wih4g = (__bf16*)(ws + 1048576);   // 8192
  __bf16* Wihd4g = (__bf16*)(ws + 1056768);  // 2048
  __bf16* Wih4f = (__bf16*)(ws + 1058816);   // 8192
  __bf16* Wihd4f = (__bf16*)(ws + 1067008);  // 2048
  float* Bg = (float*)(ws + 1069056);        // 4096
  float* Bf = (float*)(ws + 1073152);        // 4096
  __bf16* Epk = (__bf16*)(ws + 1077248);     // 131072
  __bf16* Od = (__bf16*)(ws + 1208320);      // 2560

  pack_gates_k<<<544, 64, 0, stream>>>(W_hh, W_ih, b_ih, b_hh, Wg, Wih4g, Wihd4g, Bg);
  pack_gates_k<<<544, 64, 0, stream>>>(W_hh_f, W_ih_f, b_ih_f, b_hh_f, Wf, Wih4f, Wihd4f, Bf);
  pack_misc_k<<<129, 64, 0, stream>>>(W_enc, W_out, Epk, Od);

  rnn_pp<<<128, 512, 0, stream>>>(
      sk, initx,
      (const i32x4*)Wg, Wih4g, Wihd4g, Bg,
      (const i32x4*)Wf, Wih4f, Wihd4f, Bf,
      (const bf16x8*)Epk, b_enc,
      Od, b_out,
      (float*)d_out);
}

// Round 16
// 1133.117 us; speedup vs baseline: 1.3797x; 1.0600x over previous
//
#include <hip/hip_runtime.h>

// B=2048, T=128, D=5, H=256. Two sequential LSTM scans.
// Round 16: R12 (best, 1131us) + ONE change: streamed weight loads are
// non-temporal (bypass/minimize L1 retention). The weight stream is
// 384 KB/step through a 32 KB L1 with zero intra-step reuse -- pure thrash.
// Everything else identical to R12: chunks 4,5 LDS-resident; 0,1,2,3,6,7
// streamed via laundered base (LICM defeat); chain order 0..7,x ->
// bit-identical numerics (absmax 4.88e-4). grid=128 x 512thr, 1 WG/CU,
// h in XOR-swizzled 8 KB LDS, 2 barriers/step.

typedef __bf16 bf16x8 __attribute__((ext_vector_type(8)));
typedef __bf16 bf16x4 __attribute__((ext_vector_type(4)));
typedef float f32x4 __attribute__((ext_vector_type(4)));
typedef int i32x4 __attribute__((ext_vector_type(4)));

#define MFMA16(A, B, C) __builtin_amdgcn_mfma_f32_16x16x32_bf16((A), (B), (C), 0, 0, 0)

__device__ __forceinline__ float fast_sigmoid(float x) {
  float e = __builtin_amdgcn_exp2f(-1.4426950408889634f * x);
  return __builtin_amdgcn_rcpf(1.0f + e);
}
__device__ __forceinline__ float fast_tanh(float x) {
  float e = __builtin_amdgcn_exp2f(2.8853900817779268f * x);
  return 1.0f - 2.0f * __builtin_amdgcn_rcpf(e + 1.0f);
}
__device__ __forceinline__ float lrelu(float x) { return x >= 0.0f ? x : 0.01f * x; }

__device__ __forceinline__ bf16x8 asbf(i32x4 v) {
  union { i32x4 i; bf16x8 b; } u; u.i = v; return u.b;
}

// ---------------- prep: pack weights ----------------
// Whh frag (gt,c,lane): 8 bf16 = W[g=gt*16+(lane&15)][k=c*32+(lane>>4)*8+0..7]
__global__ void pack_gates_k(const float* __restrict__ Whh, const float* __restrict__ Wih,
                             const float* __restrict__ bih, const float* __restrict__ bhh,
                             __bf16* __restrict__ wpack, __bf16* __restrict__ wih4,
                             __bf16* __restrict__ wihd4, float* __restrict__ bias) {
  int lane = threadIdx.x, blk = blockIdx.x;
  if (blk < 512) {
    int gt = blk >> 3, c = blk & 7;
    int g = gt * 16 + (lane & 15);
    int k0 = c * 32 + (lane >> 4) * 8;
    bf16x8 v;
#pragma unroll
    for (int j = 0; j < 8; ++j) v[j] = (__bf16)Whh[g * 256 + k0 + j];
    *(bf16x8*)(wpack + ((size_t)(gt * 8 + c) * 64 + lane) * 8) = v;
  } else if (blk < 528) {
    int g = (blk - 512) * 64 + lane;
    bf16x4 v;
#pragma unroll
    for (int j = 0; j < 4; ++j) v[j] = (__bf16)Wih[g * 5 + j];
    *(bf16x4*)(wih4 + (size_t)g * 4) = v;
    wihd4[g] = (__bf16)Wih[g * 5 + 4];
  } else {
    int g = (blk - 528) * 64 + lane;
    bias[g] = bih[g] + bhh[g];
  }
}

__global__ void pack_misc_k(const float* __restrict__ Wenc, const float* __restrict__ Wout,
                            __bf16* __restrict__ encpack, __bf16* __restrict__ outd) {
  int lane = threadIdx.x, blk = blockIdx.x;
  if (blk < 128) {  // W_enc[:, :256]: 16 row-tiles x 8 chunks
    int T2 = blk >> 3, c = blk & 7;
    int row = T2 * 16 + (lane & 15);
    int k0 = c * 32 + (lane >> 4) * 8;
    bf16x8 v;
#pragma unroll
    for (int j = 0; j < 8; ++j) v[j] = (__bf16)Wenc[row * 512 + k0 + j];
    *(bf16x8*)(encpack + ((size_t)(T2 * 8 + c) * 64 + lane) * 8) = v;
  } else {  // W_out (5x256) dense, row-XOR-swizzled
    for (int i = lane; i < 1280; i += 64) {
      int row = i >> 8, kk = i & 255;
      outd[row * 256 + (kk ^ (row << 3))] = (__bf16)Wout[row * 256 + kk];
    }
  }
}

// ---------------- main kernel ----------------
// non-temporal streamed loads: weights have zero L1 reuse within a step
#define LOADQ(DST, P, CA, CB)                                                        \
  _Pragma("unroll") for (int q = 0; q < 4; ++q) {                                    \
    const int gtq = q * 16 + ut2 + (P);                                              \
    DST[q] = __builtin_nontemporal_load(&Ws[(gtq * 8 + (CA)) * 64 + lane]);          \
    DST[4 + q] = __builtin_nontemporal_load(&Ws[(gtq * 8 + (CB)) * 64 + lane]);      \
  }

// one half-step: gates for tiles (q=0..3, fixed P). Chunk order 0..7,x
// (identical arithmetic to R6/R10/R12). 0-3,6,7 streamed (2 buffers, s0
// reused for 6,7); 4,5 LDS.
#define GATEPASS(P, AX, HVP)                                                         \
  {                                                                                  \
    i32x4 s0[8], s1[8];                                                              \
    LOADQ(s0, P, 0, 1);                                                              \
    LOADQ(s1, P, 2, 3);                                                              \
    const int gt0 = 0 * 16 + ut2 + (P), gt1 = 1 * 16 + ut2 + (P);                    \
    const int gt2 = 2 * 16 + ut2 + (P), gt3 = 3 * 16 + ut2 + (P);                    \
    const float bv0 = biass[gt0 * 16 + col], bv1 = biass[gt1 * 16 + col];            \
    const float bv2 = biass[gt2 * 16 + col], bv3 = biass[gt3 * 16 + col];            \
    f32x4 a0 = {bv0, bv0, bv0, bv0}, a1 = {bv1, bv1, bv1, bv1};                      \
    f32x4 a2 = {bv2, bv2, bv2, bv2}, a3 = {bv3, bv3, bv3, bv3};                      \
    { /* chunks 0,1 (s0) */                                                          \
      bf16x8 ac0 = *(const bf16x8*)(hbb + ((col * 512 + 0 * 64 + lgrp * 16) ^ xsw)); \
      a0 = MFMA16(ac0, asbf(s0[0]), a0); a1 = MFMA16(ac0, asbf(s0[1]), a1);          \
      a2 = MFMA16(ac0, asbf(s0[2]), a2); a3 = MFMA16(ac0, asbf(s0[3]), a3);          \
      bf16x8 ac1 = *(const bf16x8*)(hbb + ((col * 512 + 1 * 64 + lgrp * 16) ^ xsw)); \
      a0 = MFMA16(ac1, asbf(s0[4]), a0); a1 = MFMA16(ac1, asbf(s0[5]), a1);          \
      a2 = MFMA16(ac1, asbf(s0[6]), a2); a3 = MFMA16(ac1, asbf(s0[7]), a3);          \
    }                                                                                \
    LOADQ(s0, P, 6, 7); /* reuse s0 for chunks 6,7 (WAR keeps pressure 64) */        \
    { /* chunks 2,3 (s1) */                                                          \
      bf16x8 ac2 = *(const bf16x8*)(hbb + ((col * 512 + 2 * 64 + lgrp * 16) ^ xsw)); \
      a0 = MFMA16(ac2, asbf(s1[0]), a0); a1 = MFMA16(ac2, asbf(s1[1]), a1);          \
      a2 = MFMA16(ac2, asbf(s1[2]), a2); a3 = MFMA16(ac2, asbf(s1[3]), a3);          \
      bf16x8 ac3 = *(const bf16x8*)(hbb + ((col * 512 + 3 * 64 + lgrp * 16) ^ xsw)); \
      a0 = MFMA16(ac3, asbf(s1[4]), a0); a1 = MFMA16(ac3, asbf(s1[5]), a1);          \
      a2 = MFMA16(ac3, asbf(s1[6]), a2); a3 = MFMA16(ac3, asbf(s1[7]), a3);          \
    }                                                                                \
    _Pragma("unroll") for (int c2 = 0; c2 < 2; ++c2) { /* chunks 4,5 (LDS) */        \
      bf16x8 ac = *(const bf16x8*)(hbb + ((col * 512 + (c2 + 4) * 64 + lgrp * 16) ^ xsw)); \
      a0 = MFMA16(ac, *(const bf16x8*)&wlds[c2][gt0][lane][0], a0);                  \
      a1 = MFMA16(ac, *(const bf16x8*)&wlds[c2][gt1][lane][0], a1);                  \
      a2 = MFMA16(ac, *(const bf16x8*)&wlds[c2][gt2][lane][0], a2);                  \
      a3 = MFMA16(ac, *(const bf16x8*)&wlds[c2][gt3][lane][0], a3);                  \
    }                                                                                \
    { /* chunks 6,7 (s0 reloaded) */                                                 \
      bf16x8 ac6 = *(const bf16x8*)(hbb + ((col * 512 + 6 * 64 + lgrp * 16) ^ xsw)); \
      a0 = MFMA16(ac6, asbf(s0[0]), a0); a1 = MFMA16(ac6, asbf(s0[1]), a1);          \
      a2 = MFMA16(ac6, asbf(s0[2]), a2); a3 = MFMA16(ac6, asbf(s0[3]), a3);          \
      bf16x8 ac7 = *(const bf16x8*)(hbb + ((col * 512 + 7 * 64 + lgrp * 16) ^ xsw)); \
      a0 = MFMA16(ac7, asbf(s0[4]), a0); a1 = MFMA16(ac7, asbf(s0[5]), a1);          \
      a2 = MFMA16(ac7, asbf(s0[6]), a2); a3 = MFMA16(ac7, asbf(s0[7]), a3);          \
    }                                                                                \
    { /* x chunk last */                                                             \
      bf16x8 b0f = {}, b1f = {}, b2f = {}, b3f = {};                                 \
      if (lgrp == 0) {                                                               \
        bf16x4 w40 = *(const bf16x4*)&wih4s[gt0 * 16 + col][0];                      \
        bf16x4 w41 = *(const bf16x4*)&wih4s[gt1 * 16 + col][0];                      \
        bf16x4 w42 = *(const bf16x4*)&wih4s[gt2 * 16 + col][0];                      \
        bf16x4 w43 = *(const bf16x4*)&wih4s[gt3 * 16 + col][0];                      \
        b0f[0]=w40[0]; b0f[1]=w40[1]; b0f[2]=w40[2]; b0f[3]=w40[3];                  \
        b1f[0]=w41[0]; b1f[1]=w41[1]; b1f[2]=w41[2]; b1f[3]=w41[3];                  \
        b2f[0]=w42[0]; b2f[1]=w42[1]; b2f[2]=w42[2]; b2f[3]=w42[3];                  \
        b3f[0]=w43[0]; b3f[1]=w43[1]; b3f[2]=w43[2]; b3f[3]=w43[3];                  \
        b0f[4]=wihd4s[gt0 * 16 + col]; b1f[4]=wihd4s[gt1 * 16 + col];                \
        b2f[4]=wihd4s[gt2 * 16 + col]; b3f[4]=wihd4s[gt3 * 16 + col];                \
      }                                                                              \
      a0 = MFMA16(AX, b0f, a0); a1 = MFMA16(AX, b1f, a1);                            \
      a2 = MFMA16(AX, b2f, a2); a3 = MFMA16(AX, b3f, a3);                            \
    }                                                                                \
    _Pragma("unroll") for (int r = 0; r < 4; ++r) {                                  \
      float ig = fast_sigmoid(a0[r]);                                                \
      float fg = fast_sigmoid(a1[r]);                                                \
      float gg = fast_tanh(a2[r]);                                                   \
      float og = fast_sigmoid(a3[r]);                                                \
      float cn = fg * c_reg[P][r] + ig * gg;                                         \
      c_reg[P][r] = cn;                                                              \
      HVP[r] = og * fast_tanh(cn);                                                   \
    }                                                                                \
  }

#define HWRITE2(HV)                                                                    \
  _Pragma("unroll") for (int P = 0; P < 2; ++P)                                        \
  _Pragma("unroll") for (int r = 0; r < 4; ++r) {                                      \
    const int row = lgrp * 4 + r;                                                      \
    const int u = 32 * wv + 16 * P + col;                                              \
    *(__bf16*)(hbb + ((row * 512 + u * 2) ^ ((row & 7) << 4))) = (__bf16)HV[P][r];     \
  }

__global__ __launch_bounds__(512) void rnn_nt(
    const float* __restrict__ sk, const float* __restrict__ initx,
    const i32x4* __restrict__ Wg, const __bf16* __restrict__ Wih4g, const __bf16* __restrict__ Wihd4g,
    const float* __restrict__ Bg,
    const i32x4* __restrict__ Wf, const __bf16* __restrict__ Wih4f, const __bf16* __restrict__ Wihd4f,
    const float* __restrict__ Bf,
    const bf16x8* __restrict__ Epk, const float* __restrict__ benc,
    const __bf16* __restrict__ Od, const float* __restrict__ bout,
    float* __restrict__ out) {
  __shared__ __attribute__((aligned(16))) __bf16 wlds[2][64][64][8];  // 131072 B: chunks 4,5
  __shared__ __attribute__((aligned(16))) __bf16 wih4s[1024][4];      // 8192 B
  __shared__ __attribute__((aligned(16))) __bf16 hb[4096];            // 8192 B
  __shared__ __attribute__((aligned(16))) float biass[1024];          // 4096 B
  __shared__ __attribute__((aligned(16))) __bf16 woutd[5][256];       // 2560 B
  __shared__ __attribute__((aligned(16))) __bf16 wihd4s[1024];        // 2048 B
  __shared__ __attribute__((aligned(16))) __bf16 xts[8][16][8];       // 2048 B

  const int tid = threadIdx.x, lane = tid & 63, wv = tid >> 6;
  const int col = lane & 15, lgrp = lane >> 4;
  const int b0 = blockIdx.x * 16;
  const int ut2 = wv * 2;
  const int xsw = (col & 7) << 4;
  char* hbb = (char*)hb;
  char* wob = (char*)woutd;

  auto stage_wlds = [&](const i32x4* Wpk) {  // chunks 4,5 -> LDS
    for (int i = tid; i < 8192; i += 512) {
      int c2 = i >> 12, gt = (i >> 6) & 63, ln = i & 63;
      *(i32x4*)&wlds[c2][gt][ln][0] = Wpk[(gt * 8 + 4 + c2) * 64 + ln];
    }
  };
  auto stage_small = [&](const __bf16* w4, const __bf16* wd4, const float* Bp) {
    for (int i = tid; i < 1024; i += 512) {
      *(bf16x4*)&wih4s[i][0] = *(const bf16x4*)(w4 + (size_t)i * 4);
      wihd4s[i] = wd4[i];
      biass[i] = Bp[i];
    }
  };

  // ---------- encoder prologue ----------
  stage_wlds(Wf);
  stage_small(Wih4f, Wihd4f, Bf);
  for (int i = tid; i < 4096; i += 512) hb[i] = (__bf16)0.0f;
  for (int i = tid; i < 1024; i += 512) (&xts[0][0][0])[i] = (__bf16)0.0f;

  const i32x4* Ws = Wf;  // stream base (chunks 0-3,6,7)

  float c_reg[2][4] = {{0.f, 0.f, 0.f, 0.f}, {0.f, 0.f, 0.f, 0.f}};
  float xc0 = 0.f, xc1 = 0.f, xc2 = 0.f, xc3 = 0.f, xc4 = 0.f;
  if (lgrp == 0) {
    const float* xp = sk + (size_t)(b0 + col) * 128 * 5;
    xc0 = xp[0]; xc1 = xp[1]; xc2 = xp[2]; xc3 = xp[3]; xc4 = xp[4];
  }
  __syncthreads();

  // -------- encoder: 128 steps --------
#pragma unroll 1
  for (int t = 0; t < 128; ++t) {
    asm volatile("" : "+s"(Ws));  // launder: defeat cross-step hoist (R12 fix)
    bf16x8 ax = (bf16x8){};
    if (lgrp == 0) {
      ax[0] = (__bf16)xc0; ax[1] = (__bf16)xc1; ax[2] = (__bf16)xc2;
      ax[3] = (__bf16)xc3; ax[4] = (__bf16)xc4;
    }
    if (t < 127 && lgrp == 0) {  // prefetch x(t+1) under the MFMA chain
      const float* xp = sk + ((size_t)(b0 + col) * 128 + t + 1) * 5;
      xc0 = xp[0]; xc1 = xp[1]; xc2 = xp[2]; xc3 = xp[3]; xc4 = xp[4];
    }
    float hv[2][4];
    GATEPASS(0, ax, hv[0]);
    GATEPASS(1, ax, hv[1]);
    __syncthreads();  // all reads of h(t) done
    HWRITE2(hv);
    __syncthreads();  // h(t+1) visible
  }

  // -------- transition --------
  bf16x8 ah[8];
#pragma unroll
  for (int c = 0; c < 8; ++c)
    ah[c] = *(const bf16x8*)(hbb + ((col * 512 + c * 64 + lgrp * 16) ^ xsw));
  __syncthreads();
#pragma unroll
  for (int P = 0; P < 2; ++P)
#pragma unroll
    for (int r = 0; r < 4; ++r) {
      const int row = lgrp * 4 + r;
      const int u = 32 * wv + 16 * P + col;
      *(__bf16*)(hbb + ((row * 512 + u * 2) ^ ((row & 7) << 4))) = (__bf16)c_reg[P][r];
    }
  __syncthreads();
  bf16x8 acf[8];
#pragma unroll
  for (int c = 0; c < 8; ++c)
    acf[c] = *(const bf16x8*)(hbb + ((col * 512 + c * 64 + lgrp * 16) ^ xsw));
  __syncthreads();  // hb free

  float hvt[2][4];
#pragma unroll
  for (int p = 0; p < 2; ++p) {
    const int T2 = ut2 + p;
    const float bvh = benc[T2 * 16 + col];
    f32x4 hacc = {bvh, bvh, bvh, bvh};
    f32x4 cacc = {bvh, bvh, bvh, bvh};
#pragma unroll
    for (int c = 0; c < 8; ++c) {
      bf16x8 eb = Epk[(T2 * 8 + c) * 64 + lane];
      hacc = MFMA16(ah[c], eb, hacc);
      cacc = MFMA16(acf[c], eb, cacc);
    }
#pragma unroll
    for (int r = 0; r < 4; ++r) {
      hvt[p][r] = lrelu(hacc[r]);
      c_reg[p][r] = lrelu(cacc[r]);  // gen c(0)
    }
  }
  HWRITE2(hvt);  // gen h(0)

  // restage for generator
  stage_wlds(Wg);
  stage_small(Wih4g, Wihd4g, Bg);
  for (int i = tid; i < 1280; i += 512) (&woutd[0][0])[i] = Od[i];
  Ws = Wg;

  const float bo = (col < 5) ? bout[col] : 0.0f;
  bf16x8 ax = (bf16x8){};
  if (lgrp == 0) {
    const float* xp = initx + (size_t)(b0 + col) * 5;
    ax[0] = (__bf16)xp[0]; ax[1] = (__bf16)xp[1]; ax[2] = (__bf16)xp[2];
    ax[3] = (__bf16)xp[3]; ax[4] = (__bf16)xp[4];
  }
  __syncthreads();  // h(0) + gen stages visible

  // -------- generator: 128 steps --------
  const int orow = (col < 5) ? col : 0;
#pragma unroll 1
  for (int j = 0; j < 128; ++j) {
    asm volatile("" : "+s"(Ws));  // launder
    float hv[2][4];
    GATEPASS(0, ax, hv[0]);
    GATEPASS(1, ax, hv[1]);
    __syncthreads();  // reads of h(j) done
    HWRITE2(hv);
    __syncthreads();  // h(j+1) visible
    // out(j) = lrelu(W_out @ h(j+1) + b_out), all waves (private x-transpose)
    f32x4 oacc = {bo, bo, bo, bo};
#pragma unroll
    for (int c = 0; c < 8; ++c) {
      bf16x8 ac = *(const bf16x8*)(hbb + ((col * 512 + c * 64 + lgrp * 16) ^ xsw));
      bf16x8 wb = *(const bf16x8*)(wob + (orow * 512 + ((c * 64 + lgrp * 16) ^ (orow << 4))));
      oacc = MFMA16(ac, wb, oacc);
    }
    if (col < 5) {
#pragma unroll
      for (int r = 0; r < 4; ++r) {
        float v = lrelu(oacc[r]);
        if (wv == 0) out[((size_t)(b0 + lgrp * 4 + r) * 128 + j) * 5 + col] = v;
        xts[wv][lgrp * 4 + r][col] = (__bf16)v;  // cols 5..7 stay zero
      }
    }
    ax = (bf16x8){};
    if (lgrp == 0) ax = *(const bf16x8*)&xts[wv][col][0];
  }
}

extern "C" void kernel_launch(void* const* d_in, const int* in_sizes, int n_in,
                              void* d_out, int out_size, void* d_ws, size_t ws_size,
                              hipStream_t stream) {
  const float* sk = (const float*)d_in[0];
  const float* initx = (const float*)d_in[1];
  const float* W_ih = (const float*)d_in[2];
  const float* W_hh = (const float*)d_in[3];
  const float* b_ih = (const float*)d_in[4];
  const float* b_hh = (const float*)d_in[5];
  const float* W_ih_f = (const float*)d_in[6];
  const float* W_hh_f = (const float*)d_in[7];
  const float* b_ih_f = (const float*)d_in[8];
  const float* b_hh_f = (const float*)d_in[9];
  const float* W_enc = (const float*)d_in[14];
  const float* b_enc = (const float*)d_in[15];
  const float* W_out = (const float*)d_in[16];
  const float* b_out = (const float*)d_in[17];

  char* ws = (char*)d_ws;
  __bf16* Wg = (__bf16*)(ws + 0);            // 524288
  __bf16* Wf = (__bf16*)(ws + 524288);       // 524288
  __bf16* Wih4g = (__bf16*)(ws + 1048576);   // 8192
  __bf16* Wihd4g = (__bf16*)(ws + 1056768);  // 2048
  __bf16* Wih4f = (__bf16*)(ws + 1058816);   // 8192
  __bf16* Wihd4f = (__bf16*)(ws + 1067008);  // 2048
  float* Bg = (float*)(ws + 1069056);        // 4096
  float* Bf = (float*)(ws + 1073152);        // 4096
  __bf16* Epk = (__bf16*)(ws + 1077248);     // 131072
  __bf16* Od = (__bf16*)(ws + 1208320);      // 2560

  pack_gates_k<<<544, 64, 0, stream>>>(W_hh, W_ih, b_ih, b_hh, Wg, Wih4g, Wihd4g, Bg);
  pack_gates_k<<<544, 64, 0, stream>>>(W_hh_f, W_ih_f, b_ih_f, b_hh_f, Wf, Wih4f, Wihd4f, Bf);
  pack_misc_k<<<129, 64, 0, stream>>>(W_enc, W_out, Epk, Od);

  rnn_nt<<<128, 512, 0, stream>>>(
      sk, initx,
      (const i32x4*)Wg, Wih4g, Wihd4g, Bg,
      (const i32x4*)Wf, Wih4f, Wihd4f, Bf,
      (const bf16x8*)Epk, b_enc,
      Od, b_out,
      (float*)d_out);
}